// Round 2
// baseline (393.068 us; speedup 1.0000x reference)
//
#include <hip/hip_runtime.h>

// S4 layer: B=8, L=4096, D=1024, N=128
// R4: gemm1 rebuilt for occupancy: 16-row tiles x 2048 blocks (8 blocks/CU,
//     ~32 waves/CU), direct-fragment loads (A shared by 4 waves via L1,
//     B L2-resident), 2 MFMA/iter/wave, acc=8 VGPR. No LDS, no barriers.
//     gemm2 / scans / prep unchanged from R3.
//   prep:  final_state (exact fp32) + Bw,Cw -> f16
//   gemm1: xp = x @ Bw^T   (2048 blocks of 16x128, streaming)
//   scan:  3-phase chunked parallel scan (fp32), CHUNK=32
//   gemm2: y = hs @ Cw^T + x*Dp  (2048 blocks of 128x128, K=128, direct frags)

typedef _Float16 half8 __attribute__((ext_vector_type(8)));
typedef _Float16 half4 __attribute__((ext_vector_type(4)));
typedef float f32x4 __attribute__((ext_vector_type(4)));

#define BDIM 8
#define LDIM 4096
#define DDIM 1024
#define NDIM 128
#define MTOT (BDIM * LDIM)       // 32768
#define CHUNK 32
#define NCHUNK (LDIM / CHUNK)    // 128
#define TOTCHUNK (BDIM * NCHUNK) // 1024

// ---------------- prep: final_state + convert Bw,Cw to f16 ----------------
__global__ __launch_bounds__(256) void prep(const float* __restrict__ x,
                                            const float* __restrict__ Bw,
                                            const float* __restrict__ Cw,
                                            _Float16* __restrict__ Bwh,
                                            _Float16* __restrict__ Cwh,
                                            float* __restrict__ out) {
    const int blk = blockIdx.x;
    const int t = threadIdx.x;
    if (blk < 128) {
        // final_state: out[b][n] = mean_b' dot(x[b',L-1,:], Bw[n,:])   (exact fp32)
        const int n = blk;
        float s = 0.f;
        const float* br = Bw + n * DDIM;
        for (int b = 0; b < BDIM; ++b) {
            const float* xr = x + ((size_t)b * LDIM + (LDIM - 1)) * DDIM;
            for (int k = t; k < DDIM; k += 256)
                s = fmaf(xr[k], br[k], s);
        }
        __shared__ float red[256];
        red[t] = s;
        __syncthreads();
        for (int off = 128; off > 0; off >>= 1) {
            if (t < off) red[t] += red[t + off];
            __syncthreads();
        }
        if (t == 0) {
            float v = red[0] * 0.125f;
            for (int b = 0; b < BDIM; ++b)
                out[(size_t)MTOT * DDIM + b * NDIM + n] = v;
        }
    } else {
        // convert 262144 fp32 (Bw 131072 then Cw 131072) to f16; 64 blocks x 4096 elems
        const int base = (blk - 128) * 4096;
#pragma unroll
        for (int j = 0; j < 4; ++j) {
            int e = base + j * 1024 + t * 4;
            const float* src;
            _Float16* dst;
            if (e < 131072) { src = Bw + e; dst = Bwh + e; }
            else            { src = Cw + (e - 131072); dst = Cwh + (e - 131072); }
            float4 v = *reinterpret_cast<const float4*>(src);
            half4 h = { (_Float16)v.x, (_Float16)v.y, (_Float16)v.z, (_Float16)v.w };
            *reinterpret_cast<half4*>(dst) = h;
        }
    }
}

// ---------------- GEMM1: xp[m][n] = sum_k x[m][k] * Bw[n][k] ----------------
// 16-row tile, 2048 blocks (8 blocks/CU), 4 waves each owning a 32-col slice.
// A frag (16 rows) shared by all 4 waves -> redundant loads hit L1.
// B frag = 16B contiguous span of Bwh row (L2-resident, 256 KB total).
// acc = 2 x f32x4 = 8 VGPRs -> low pressure -> full occupancy.
__global__ __launch_bounds__(256) void gemm1(const float* __restrict__ x,
                                             const _Float16* __restrict__ Bwh,
                                             float* __restrict__ xp) {
    const int t = threadIdx.x;
    const int row0 = blockIdx.x * 16;
    const int wave = t >> 6, lane = t & 63;
    const int lrow = lane & 15, kq = (lane >> 4) * 8;

    f32x4 acc[2] = {};
    const float* ap = x + (size_t)(row0 + lrow) * DDIM + kq;
    const _Float16* bp = Bwh + (size_t)(wave * 32 + lrow) * DDIM + kq;

#pragma unroll 2
    for (int kk = 0; kk < DDIM; kk += 32) {
        half8 bf0 = *reinterpret_cast<const half8*>(bp + kk);
        half8 bf1 = *reinterpret_cast<const half8*>(bp + 16 * DDIM + kk);
        float4 v0 = *reinterpret_cast<const float4*>(ap + kk);
        float4 v1 = *reinterpret_cast<const float4*>(ap + kk + 4);
        half8 af = { (_Float16)v0.x, (_Float16)v0.y, (_Float16)v0.z, (_Float16)v0.w,
                     (_Float16)v1.x, (_Float16)v1.y, (_Float16)v1.z, (_Float16)v1.w };
        acc[0] = __builtin_amdgcn_mfma_f32_16x16x32_f16(af, bf0, acc[0], 0, 0, 0);
        acc[1] = __builtin_amdgcn_mfma_f32_16x16x32_f16(af, bf1, acc[1], 0, 0, 0);
    }

    const int q4 = (lane >> 4) * 4;
#pragma unroll
    for (int ct = 0; ct < 2; ++ct) {
        int col = wave * 32 + ct * 16 + lrow;
#pragma unroll
        for (int i = 0; i < 4; ++i)
            xp[(row0 + q4 + i) * NDIM + col] = acc[ct][i];
    }
}

// ---------------- scan phase 1: per-chunk aggregates ----------------
__global__ void scan_agg(const float* __restrict__ xp, const float* __restrict__ logA,
                         float* __restrict__ agg) {
    const int chunk = blockIdx.x;
    const int n = threadIdx.x;
    const float A = expf(logA[n]);
    const float* u = xp + (size_t)chunk * CHUNK * NDIM + n;
    float h = 0.f;
#pragma unroll
    for (int j = 0; j < CHUNK; ++j)
        h = fmaf(A, h, u[j * NDIM]);
    agg[chunk * NDIM + n] = h;
}

// ---------------- scan phase 2: carries across chunks ----------------
__global__ void scan_carry(const float* __restrict__ agg, const float* __restrict__ logA,
                           float* __restrict__ hprev) {
    const int idx = blockIdx.x * blockDim.x + threadIdx.x;  // 1024
    const int b = idx >> 7, n = idx & 127;
    const float Ac = expf((float)CHUNK * logA[n]);
    float c = 0.f;
    for (int ch = 0; ch < NCHUNK; ++ch) {
        int g = (b * NCHUNK + ch) * NDIM + n;
        hprev[g] = c;
        c = fmaf(Ac, c, agg[g]);
    }
}

// ---------------- scan phase 3: final scan, write hs (f16) ----------------
__global__ void scan_final(const float* __restrict__ xp, const float* __restrict__ logA,
                           const float* __restrict__ hprev, _Float16* __restrict__ hs) {
    const int chunk = blockIdx.x;
    const int n = threadIdx.x;
    const float A = expf(logA[n]);
    float h = hprev[chunk * NDIM + n];
    const float* u = xp + (size_t)chunk * CHUNK * NDIM + n;
    _Float16* o = hs + (size_t)chunk * CHUNK * NDIM + n;
#pragma unroll
    for (int j = 0; j < CHUNK; ++j) {
        h = fmaf(A, h, u[j * NDIM]);
        o[j * NDIM] = (_Float16)h;
    }
}

// ---------------- GEMM2: y[m][d] = sum_n hs[m][n]*Cw[d][n] + x[m][d]*Dp[d] ----------------
// 128x128 tile, K=128 single shot. Direct fragment loads (hs L3-resident for
// the 8x column re-reads, Cwh L2-resident). LDS only for the coalesced
// float4 transpose epilogue (34 KB -> 4 blocks/CU).
#define BUFW 132
__global__ __launch_bounds__(256, 4) void gemm2(const _Float16* __restrict__ hs,
                                                const _Float16* __restrict__ Cwh,
                                                const float* __restrict__ x,
                                                const float* __restrict__ Dp,
                                                float* __restrict__ y) {
    __shared__ float buf[64 * BUFW];             // 33.8 KB epilogue transpose buffer
    __shared__ __align__(16) float DpS[128];

    const int t = threadIdx.x;
    const int row0 = blockIdx.x * 128;
    const int col0 = blockIdx.y * 128;
    const int wave = t >> 6, lane = t & 63;
    const int wr = (wave >> 1) * 64, wc = (wave & 1) * 64;
    const int lrow = lane & 15, kq = (lane >> 4) * 8;

    if (t < 128) DpS[t] = Dp[col0 + t];

    const _Float16* ha = hs + (size_t)(row0 + wr + lrow) * NDIM + kq;
    const _Float16* cb = Cwh + (size_t)(col0 + wc + lrow) * NDIM + kq;

    f32x4 acc[4][4] = {};
#pragma unroll
    for (int kb = 0; kb < 4; ++kb) {
        half8 bf[4], af[4];
#pragma unroll
        for (int ct = 0; ct < 4; ++ct)
            bf[ct] = *reinterpret_cast<const half8*>(cb + (size_t)ct * 16 * NDIM + kb * 32);
#pragma unroll
        for (int rt = 0; rt < 4; ++rt)
            af[rt] = *reinterpret_cast<const half8*>(ha + (size_t)rt * 16 * NDIM + kb * 32);
#pragma unroll
        for (int rt = 0; rt < 4; ++rt)
#pragma unroll
            for (int ct = 0; ct < 4; ++ct)
                acc[rt][ct] = __builtin_amdgcn_mfma_f32_16x16x32_f16(af[rt], bf[ct], acc[rt][ct], 0, 0, 0);
    }

    // epilogue: two 64-row halves through LDS fp32 buffer [64][BUFW]
    const int q4 = (lane >> 4) * 4;
#pragma unroll
    for (int half_ = 0; half_ < 2; ++half_) {
        __syncthreads();
        if ((wr >> 6) == half_) {
#pragma unroll
            for (int rt = 0; rt < 4; ++rt)
#pragma unroll
                for (int ct = 0; ct < 4; ++ct) {
                    int col = wc + ct * 16 + lrow;
#pragma unroll
                    for (int i = 0; i < 4; ++i)
                        buf[(rt * 16 + q4 + i) * BUFW + col] = acc[rt][ct][i];
                }
        }
        __syncthreads();
#pragma unroll
        for (int j = 0; j < 8; ++j) {
            int idx = t + 256 * j;
            int row = idx >> 5, c4 = idx & 31;
            int grow = row0 + half_ * 64 + row;
            float4 a = *reinterpret_cast<const float4*>(&buf[row * BUFW + c4 * 4]);
            float4 xv = *reinterpret_cast<const float4*>(&x[(size_t)grow * DDIM + col0 + c4 * 4]);
            float4 dp = *reinterpret_cast<const float4*>(&DpS[c4 * 4]);
            float4 o;
            o.x = a.x + xv.x * dp.x;
            o.y = a.y + xv.y * dp.y;
            o.z = a.z + xv.z * dp.z;
            o.w = a.w + xv.w * dp.w;
            *reinterpret_cast<float4*>(&y[(size_t)grow * DDIM + col0 + c4 * 4]) = o;
        }
    }
}

extern "C" void kernel_launch(void* const* d_in, const int* in_sizes, int n_in,
                              void* d_out, int out_size, void* d_ws, size_t ws_size,
                              hipStream_t stream) {
    const float* x    = (const float*)d_in[0];   // (8, 4096, 1024)
    const float* Bw   = (const float*)d_in[1];   // (128, 1024)
    const float* Cw   = (const float*)d_in[2];   // (1024, 128)
    const float* logA = (const float*)d_in[3];   // (128,)
    const float* Dp   = (const float*)d_in[4];   // (1024,)
    float* out = (float*)d_out;                  // y (33554432) + final_state (1024)

    char* ws = (char*)d_ws;
    float*    xp    = (float*)   (ws);                       // 16,777,216 B
    _Float16* hs    = (_Float16*)(ws + 16777216);            //  8,388,608 B
    float*    agg   = (float*)   (ws + 25165824);            //    524,288 B
    float*    hprev = (float*)   (ws + 25690112);            //    524,288 B
    _Float16* Bwh   = (_Float16*)(ws + 26214400);            //    262,144 B
    _Float16* Cwh   = (_Float16*)(ws + 26476544);            //    262,144 B

    prep<<<192, 256, 0, stream>>>(x, Bw, Cw, Bwh, Cwh, out);
    gemm1<<<MTOT / 16, 256, 0, stream>>>(x, Bwh, xp);
    scan_agg<<<TOTCHUNK, 128, 0, stream>>>(xp, logA, agg);
    scan_carry<<<4, 256, 0, stream>>>(agg, logA, hprev);
    scan_final<<<TOTCHUNK, 128, 0, stream>>>(xp, logA, hprev, hs);
    gemm2<<<dim3(MTOT / 128, DDIM / 128), 256, 0, stream>>>(hs, Cwh, x, Dp, out);
}

// Round 3
// 343.623 us; speedup vs baseline: 1.1439x; 1.1439x over previous
//
#include <hip/hip_runtime.h>

// S4 layer: B=8, L=4096, D=1024, N=128
// R5: gemm1 back to LDS/DMA-staged (R2-proven) with 3 fixes:
//     32-row tiles (1024 blocks, 4 blk/CU, 16 waves/CU), BK=64 (16 iters),
//     T2 XOR-swizzled LDS (B via pre-swizzled DMA source, A via swizzled
//     reg-stage write). Scans (CHUNK=32) / gemm2 / prep unchanged from R4.
//   prep:  final_state (exact fp32) + Bw,Cw -> f16
//   gemm1: xp = x @ Bw^T   (1024 blocks of 32x128, BK=64, staged)
//   scan:  3-phase chunked parallel scan (fp32), CHUNK=32
//   gemm2: y = hs @ Cw^T + x*Dp  (2048 blocks of 128x128, K=128, direct frags)

typedef _Float16 half8 __attribute__((ext_vector_type(8)));
typedef _Float16 half4 __attribute__((ext_vector_type(4)));
typedef float f32x4 __attribute__((ext_vector_type(4)));

#define BDIM 8
#define LDIM 4096
#define DDIM 1024
#define NDIM 128
#define MTOT (BDIM * LDIM)       // 32768
#define CHUNK 32
#define NCHUNK (LDIM / CHUNK)    // 128
#define TOTCHUNK (BDIM * NCHUNK) // 1024

__device__ __forceinline__ void dma16(const void* g, void* l) {
    __builtin_amdgcn_global_load_lds((const __attribute__((address_space(1))) void*)g,
                                     (__attribute__((address_space(3))) void*)l, 16, 0, 0);
}

// ---------------- prep: final_state + convert Bw,Cw to f16 ----------------
__global__ __launch_bounds__(256) void prep(const float* __restrict__ x,
                                            const float* __restrict__ Bw,
                                            const float* __restrict__ Cw,
                                            _Float16* __restrict__ Bwh,
                                            _Float16* __restrict__ Cwh,
                                            float* __restrict__ out) {
    const int blk = blockIdx.x;
    const int t = threadIdx.x;
    if (blk < 128) {
        // final_state: out[b][n] = mean_b' dot(x[b',L-1,:], Bw[n,:])   (exact fp32)
        const int n = blk;
        float s = 0.f;
        const float* br = Bw + n * DDIM;
        for (int b = 0; b < BDIM; ++b) {
            const float* xr = x + ((size_t)b * LDIM + (LDIM - 1)) * DDIM;
            for (int k = t; k < DDIM; k += 256)
                s = fmaf(xr[k], br[k], s);
        }
        __shared__ float red[256];
        red[t] = s;
        __syncthreads();
        for (int off = 128; off > 0; off >>= 1) {
            if (t < off) red[t] += red[t + off];
            __syncthreads();
        }
        if (t == 0) {
            float v = red[0] * 0.125f;
            for (int b = 0; b < BDIM; ++b)
                out[(size_t)MTOT * DDIM + b * NDIM + n] = v;
        }
    } else {
        // convert 262144 fp32 (Bw 131072 then Cw 131072) to f16; 64 blocks x 4096 elems
        const int base = (blk - 128) * 4096;
#pragma unroll
        for (int j = 0; j < 4; ++j) {
            int e = base + j * 1024 + t * 4;
            const float* src;
            _Float16* dst;
            if (e < 131072) { src = Bw + e; dst = Bwh + e; }
            else            { src = Cw + (e - 131072); dst = Cwh + (e - 131072); }
            float4 v = *reinterpret_cast<const float4*>(src);
            half4 h = { (_Float16)v.x, (_Float16)v.y, (_Float16)v.z, (_Float16)v.w };
            *reinterpret_cast<half4*>(dst) = h;
        }
    }
}

// ---------------- GEMM1: xp[m][n] = sum_k x[m][k] * Bw[n][k] ----------------
// 32x128 tile, BK=64, 4 waves (2 row-halves x 2 col-halves; each 16x64).
// Grid 1024 -> 4 blocks/CU, 16 waves/CU. LDS 20 KB.
// A: fp32 global -> reg cvt -> swizzled ds_write. B: DMA with pre-swizzled
// global source (linear LDS dest). Reads XOR-swizzled: chunk ^= (row&7)
// -> 2-way bank aliasing (free) instead of 8/16-way.
__global__ __launch_bounds__(256, 4) void gemm1(const float* __restrict__ x,
                                                const _Float16* __restrict__ Bwh,
                                                float* __restrict__ xp) {
    __shared__ _Float16 As[32 * 64];    // 4 KB, swizzled
    __shared__ _Float16 Bs[128 * 64];   // 16 KB, swizzled
    const int t = threadIdx.x;
    const int row0 = blockIdx.x * 32;
    const int wave = t >> 6, lane = t & 63;
    const int wr = (wave >> 1) * 16, wc = (wave & 1) * 64;
    const int lrow = lane & 15, kq = (lane >> 4) * 8;
    const int kc = kq >> 3;             // k-chunk index within 32-k slice (0..3)

    f32x4 acc[4] = {};

    for (int kk = 0; kk < DDIM; kk += 64) {
        // B-tile: 128x64 f16 via DMA, source column pre-swizzled so that the
        // linear LDS write lands the swizzled layout (rule: both-sides-or-neither).
#pragma unroll
        for (int inst = 0; inst < 4; ++inst) {
            int s = inst * 256 + t;
            int r = s >> 3;
            int cs = (s & 7) ^ (r & 7);           // inverse-swizzled source chunk
            dma16(&Bwh[(size_t)r * DDIM + kk + cs * 8], &Bs[(inst * 256 + wave * 64) * 8]);
        }
        // A-tile: 32x64 fp32 -> f16, swizzled write (2 float4 per thread)
#pragma unroll
        for (int j = 0; j < 2; ++j) {
            int s = t + 256 * j;
            int r = s >> 4, c4 = s & 15;
            float4 v = *reinterpret_cast<const float4*>(&x[(size_t)(row0 + r) * DDIM + kk + c4 * 4]);
            half4 h = { (_Float16)v.x, (_Float16)v.y, (_Float16)v.z, (_Float16)v.w };
            int pc = (c4 >> 1) ^ (r & 7);         // swizzled 16B-chunk
            *reinterpret_cast<half4*>(&As[r * 64 + pc * 8 + (c4 & 1) * 4]) = h;
        }
        __syncthreads();

        half8 af[2], bf[2][4];
        const int arow = wr + lrow;
#pragma unroll
        for (int ks = 0; ks < 2; ++ks) {
            af[ks] = *reinterpret_cast<const half8*>(&As[arow * 64 + ((ks * 4 + kc) ^ (arow & 7)) * 8]);
#pragma unroll
            for (int ct = 0; ct < 4; ++ct) {
                int brow = wc + ct * 16 + lrow;
                bf[ks][ct] = *reinterpret_cast<const half8*>(&Bs[brow * 64 + ((ks * 4 + kc) ^ (brow & 7)) * 8]);
            }
        }
#pragma unroll
        for (int ks = 0; ks < 2; ++ks)
#pragma unroll
            for (int ct = 0; ct < 4; ++ct)
                acc[ct] = __builtin_amdgcn_mfma_f32_16x16x32_f16(af[ks], bf[ks][ct], acc[ct], 0, 0, 0);
        __syncthreads();
    }

    const int q4 = (lane >> 4) * 4;
#pragma unroll
    for (int ct = 0; ct < 4; ++ct) {
        int col = wc + ct * 16 + lrow;
#pragma unroll
        for (int i = 0; i < 4; ++i)
            xp[(row0 + wr + q4 + i) * NDIM + col] = acc[ct][i];
    }
}

// ---------------- scan phase 1: per-chunk aggregates ----------------
__global__ void scan_agg(const float* __restrict__ xp, const float* __restrict__ logA,
                         float* __restrict__ agg) {
    const int chunk = blockIdx.x;
    const int n = threadIdx.x;
    const float A = expf(logA[n]);
    const float* u = xp + (size_t)chunk * CHUNK * NDIM + n;
    float h = 0.f;
#pragma unroll
    for (int j = 0; j < CHUNK; ++j)
        h = fmaf(A, h, u[j * NDIM]);
    agg[chunk * NDIM + n] = h;
}

// ---------------- scan phase 2: carries across chunks ----------------
__global__ void scan_carry(const float* __restrict__ agg, const float* __restrict__ logA,
                           float* __restrict__ hprev) {
    const int idx = blockIdx.x * blockDim.x + threadIdx.x;  // 1024
    const int b = idx >> 7, n = idx & 127;
    const float Ac = expf((float)CHUNK * logA[n]);
    float c = 0.f;
    for (int ch = 0; ch < NCHUNK; ++ch) {
        int g = (b * NCHUNK + ch) * NDIM + n;
        hprev[g] = c;
        c = fmaf(Ac, c, agg[g]);
    }
}

// ---------------- scan phase 3: final scan, write hs (f16) ----------------
__global__ void scan_final(const float* __restrict__ xp, const float* __restrict__ logA,
                           const float* __restrict__ hprev, _Float16* __restrict__ hs) {
    const int chunk = blockIdx.x;
    const int n = threadIdx.x;
    const float A = expf(logA[n]);
    float h = hprev[chunk * NDIM + n];
    const float* u = xp + (size_t)chunk * CHUNK * NDIM + n;
    _Float16* o = hs + (size_t)chunk * CHUNK * NDIM + n;
#pragma unroll
    for (int j = 0; j < CHUNK; ++j) {
        h = fmaf(A, h, u[j * NDIM]);
        o[j * NDIM] = (_Float16)h;
    }
}

// ---------------- GEMM2: y[m][d] = sum_n hs[m][n]*Cw[d][n] + x[m][d]*Dp[d] ----------------
// 128x128 tile, K=128 single shot. Direct fragment loads (hs L3-resident for
// the 8x column re-reads, Cwh L2-resident). LDS only for the coalesced
// float4 transpose epilogue (34 KB -> 4 blocks/CU).
#define BUFW 132
__global__ __launch_bounds__(256, 4) void gemm2(const _Float16* __restrict__ hs,
                                                const _Float16* __restrict__ Cwh,
                                                const float* __restrict__ x,
                                                const float* __restrict__ Dp,
                                                float* __restrict__ y) {
    __shared__ float buf[64 * BUFW];             // 33.8 KB epilogue transpose buffer
    __shared__ __align__(16) float DpS[128];

    const int t = threadIdx.x;
    const int row0 = blockIdx.x * 128;
    const int col0 = blockIdx.y * 128;
    const int wave = t >> 6, lane = t & 63;
    const int wr = (wave >> 1) * 64, wc = (wave & 1) * 64;
    const int lrow = lane & 15, kq = (lane >> 4) * 8;

    if (t < 128) DpS[t] = Dp[col0 + t];

    const _Float16* ha = hs + (size_t)(row0 + wr + lrow) * NDIM + kq;
    const _Float16* cb = Cwh + (size_t)(col0 + wc + lrow) * NDIM + kq;

    f32x4 acc[4][4] = {};
#pragma unroll
    for (int kb = 0; kb < 4; ++kb) {
        half8 bf[4], af[4];
#pragma unroll
        for (int ct = 0; ct < 4; ++ct)
            bf[ct] = *reinterpret_cast<const half8*>(cb + (size_t)ct * 16 * NDIM + kb * 32);
#pragma unroll
        for (int rt = 0; rt < 4; ++rt)
            af[rt] = *reinterpret_cast<const half8*>(ha + (size_t)rt * 16 * NDIM + kb * 32);
#pragma unroll
        for (int rt = 0; rt < 4; ++rt)
#pragma unroll
            for (int ct = 0; ct < 4; ++ct)
                acc[rt][ct] = __builtin_amdgcn_mfma_f32_16x16x32_f16(af[rt], bf[ct], acc[rt][ct], 0, 0, 0);
    }

    // epilogue: two 64-row halves through LDS fp32 buffer [64][BUFW]
    const int q4 = (lane >> 4) * 4;
#pragma unroll
    for (int half_ = 0; half_ < 2; ++half_) {
        __syncthreads();
        if ((wr >> 6) == half_) {
#pragma unroll
            for (int rt = 0; rt < 4; ++rt)
#pragma unroll
                for (int ct = 0; ct < 4; ++ct) {
                    int col = wc + ct * 16 + lrow;
#pragma unroll
                    for (int i = 0; i < 4; ++i)
                        buf[(rt * 16 + q4 + i) * BUFW + col] = acc[rt][ct][i];
                }
        }
        __syncthreads();
#pragma unroll
        for (int j = 0; j < 8; ++j) {
            int idx = t + 256 * j;
            int row = idx >> 5, c4 = idx & 31;
            int grow = row0 + half_ * 64 + row;
            float4 a = *reinterpret_cast<const float4*>(&buf[row * BUFW + c4 * 4]);
            float4 xv = *reinterpret_cast<const float4*>(&x[(size_t)grow * DDIM + col0 + c4 * 4]);
            float4 dp = *reinterpret_cast<const float4*>(&DpS[c4 * 4]);
            float4 o;
            o.x = a.x + xv.x * dp.x;
            o.y = a.y + xv.y * dp.y;
            o.z = a.z + xv.z * dp.z;
            o.w = a.w + xv.w * dp.w;
            *reinterpret_cast<float4*>(&y[(size_t)grow * DDIM + col0 + c4 * 4]) = o;
        }
    }
}

extern "C" void kernel_launch(void* const* d_in, const int* in_sizes, int n_in,
                              void* d_out, int out_size, void* d_ws, size_t ws_size,
                              hipStream_t stream) {
    const float* x    = (const float*)d_in[0];   // (8, 4096, 1024)
    const float* Bw   = (const float*)d_in[1];   // (128, 1024)
    const float* Cw   = (const float*)d_in[2];   // (1024, 128)
    const float* logA = (const float*)d_in[3];   // (128,)
    const float* Dp   = (const float*)d_in[4];   // (1024,)
    float* out = (float*)d_out;                  // y (33554432) + final_state (1024)

    char* ws = (char*)d_ws;
    float*    xp    = (float*)   (ws);                       // 16,777,216 B
    _Float16* hs    = (_Float16*)(ws + 16777216);            //  8,388,608 B
    float*    agg   = (float*)   (ws + 25165824);            //    524,288 B
    float*    hprev = (float*)   (ws + 25690112);            //    524,288 B
    _Float16* Bwh   = (_Float16*)(ws + 26214400);            //    262,144 B
    _Float16* Cwh   = (_Float16*)(ws + 26476544);            //    262,144 B

    prep<<<192, 256, 0, stream>>>(x, Bw, Cw, Bwh, Cwh, out);
    gemm1<<<MTOT / 32, 256, 0, stream>>>(x, Bwh, xp);
    scan_agg<<<TOTCHUNK, 128, 0, stream>>>(xp, logA, agg);
    scan_carry<<<4, 256, 0, stream>>>(agg, logA, hprev);
    scan_final<<<TOTCHUNK, 128, 0, stream>>>(xp, logA, hprev, hs);
    gemm2<<<dim3(MTOT / 128, DDIM / 128), 256, 0, stream>>>(hs, Cwh, x, Dp, out);
}

// Round 5
// 341.627 us; speedup vs baseline: 1.1506x; 1.0058x over previous
//
#include <hip/hip_runtime.h>

// S4 layer: B=8, L=4096, D=1024, N=128
// R7 = R6 with the gemm1 epilogue-copy bug fixed (j<16 -> j<4; 32-row tile
//      is 1024 float4s, not 4096 — the j<16 loop stomped neighbors' xp rows
//      and read past the LDS buffer).
//   (1) gemm1 at 8 blocks/CU (launch_bounds(256,8)) with scan_agg fused
//       into its epilogue (tile == chunk).
//   (2) gemm2 DMA-staged hs panel ([128][128] f16, XOR-swizzled via
//       pre-swizzled source), Cwh fragments direct from L2, 4 blocks/CU,
//       bijective XCD swizzle (XCD c owns row-panels c*32..c*32+31).
//   (3) scan_carry unroll-8. scan_final/prep unchanged.

typedef _Float16 half8 __attribute__((ext_vector_type(8)));
typedef _Float16 half4 __attribute__((ext_vector_type(4)));
typedef float f32x4 __attribute__((ext_vector_type(4)));

#define BDIM 8
#define LDIM 4096
#define DDIM 1024
#define NDIM 128
#define MTOT (BDIM * LDIM)       // 32768
#define CHUNK 32
#define NCHUNK (LDIM / CHUNK)    // 128
#define TOTCHUNK (BDIM * NCHUNK) // 1024

__device__ __forceinline__ void dma16(const void* g, void* l) {
    __builtin_amdgcn_global_load_lds((const __attribute__((address_space(1))) void*)g,
                                     (__attribute__((address_space(3))) void*)l, 16, 0, 0);
}

// ---------------- prep: final_state + convert Bw,Cw to f16 ----------------
__global__ __launch_bounds__(256) void prep(const float* __restrict__ x,
                                            const float* __restrict__ Bw,
                                            const float* __restrict__ Cw,
                                            _Float16* __restrict__ Bwh,
                                            _Float16* __restrict__ Cwh,
                                            float* __restrict__ out) {
    const int blk = blockIdx.x;
    const int t = threadIdx.x;
    if (blk < 128) {
        const int n = blk;
        float s = 0.f;
        const float* br = Bw + n * DDIM;
        for (int b = 0; b < BDIM; ++b) {
            const float* xr = x + ((size_t)b * LDIM + (LDIM - 1)) * DDIM;
            for (int k = t; k < DDIM; k += 256)
                s = fmaf(xr[k], br[k], s);
        }
        __shared__ float red[256];
        red[t] = s;
        __syncthreads();
        for (int off = 128; off > 0; off >>= 1) {
            if (t < off) red[t] += red[t + off];
            __syncthreads();
        }
        if (t == 0) {
            float v = red[0] * 0.125f;
            for (int b = 0; b < BDIM; ++b)
                out[(size_t)MTOT * DDIM + b * NDIM + n] = v;
        }
    } else {
        const int base = (blk - 128) * 4096;
#pragma unroll
        for (int j = 0; j < 4; ++j) {
            int e = base + j * 1024 + t * 4;
            const float* src;
            _Float16* dst;
            if (e < 131072) { src = Bw + e; dst = Bwh + e; }
            else            { src = Cw + (e - 131072); dst = Cwh + (e - 131072); }
            float4 v = *reinterpret_cast<const float4*>(src);
            half4 h = { (_Float16)v.x, (_Float16)v.y, (_Float16)v.z, (_Float16)v.w };
            *reinterpret_cast<half4*>(dst) = h;
        }
    }
}

// ---------------- GEMM1 + fused scan_agg ----------------
// xp[m][n] = sum_k x[m][k]*Bw[n][k]; agg[chunk][n] = scan-aggregate of tile.
// 32x128 tile == one scan chunk. BK=64, 4 waves (2x2 of 16x64), swizzled LDS.
// 20 KB LDS, VGPR target <= 64 -> 8 blocks/CU (32 waves/CU).
__global__ __launch_bounds__(256, 8) void gemm1(const float* __restrict__ x,
                                                const _Float16* __restrict__ Bwh,
                                                const float* __restrict__ logA,
                                                float* __restrict__ xp,
                                                float* __restrict__ agg) {
    __shared__ _Float16 As[32 * 64];    // 4 KB, swizzled
    __shared__ _Float16 Bs[128 * 64];   // 16 KB, swizzled; reused as f32 tile buf
    const int t = threadIdx.x;
    const int row0 = blockIdx.x * 32;
    const int wave = t >> 6, lane = t & 63;
    const int wr = (wave >> 1) * 16, wc = (wave & 1) * 64;
    const int lrow = lane & 15, kq = (lane >> 4) * 8;
    const int kc = kq >> 3;

    f32x4 acc[4] = {};

    for (int kk = 0; kk < DDIM; kk += 64) {
        // B-tile: 128x64 f16 DMA, pre-swizzled source chunk (linear LDS dest)
#pragma unroll
        for (int inst = 0; inst < 4; ++inst) {
            int s = inst * 256 + t;
            int r = s >> 3;
            int cs = (s & 7) ^ (r & 7);
            dma16(&Bwh[(size_t)r * DDIM + kk + cs * 8], &Bs[(inst * 256 + wave * 64) * 8]);
        }
        // A-tile: 32x64 fp32 -> f16, swizzled ds_write
#pragma unroll
        for (int j = 0; j < 2; ++j) {
            int s = t + 256 * j;
            int r = s >> 4, c4 = s & 15;
            float4 v = *reinterpret_cast<const float4*>(&x[(size_t)(row0 + r) * DDIM + kk + c4 * 4]);
            half4 h = { (_Float16)v.x, (_Float16)v.y, (_Float16)v.z, (_Float16)v.w };
            int pc = (c4 >> 1) ^ (r & 7);
            *reinterpret_cast<half4*>(&As[r * 64 + pc * 8 + (c4 & 1) * 4]) = h;
        }
        __syncthreads();

        const int arow = wr + lrow;
#pragma unroll
        for (int ks = 0; ks < 2; ++ks) {
            half8 af = *reinterpret_cast<const half8*>(&As[arow * 64 + ((ks * 4 + kc) ^ (arow & 7)) * 8]);
            half8 bf[4];
#pragma unroll
            for (int ct = 0; ct < 4; ++ct) {
                int brow = wc + ct * 16 + lrow;
                bf[ct] = *reinterpret_cast<const half8*>(&Bs[brow * 64 + ((ks * 4 + kc) ^ (brow & 7)) * 8]);
            }
#pragma unroll
            for (int ct = 0; ct < 4; ++ct)
                acc[ct] = __builtin_amdgcn_mfma_f32_16x16x32_f16(af, bf[ct], acc[ct], 0, 0, 0);
        }
        __syncthreads();
    }

    // epilogue: scatter acc -> LDS f32 tile, then coalesced xp write + fused agg
    float* tb = (float*)Bs;             // 32x128 f32 = 16 KB
    const int q4 = (lane >> 4) * 4;
#pragma unroll
    for (int ct = 0; ct < 4; ++ct) {
        int col = wc + ct * 16 + lrow;
#pragma unroll
        for (int i = 0; i < 4; ++i)
            tb[(wr + q4 + i) * NDIM + col] = acc[ct][i];
    }
    __syncthreads();
    // 32x128 f32 = 1024 float4 -> 4 iterations of 256 threads
#pragma unroll
    for (int j = 0; j < 4; ++j) {
        int idx = t + 256 * j;
        int row = idx >> 5, c4 = idx & 31;
        *reinterpret_cast<float4*>(&xp[(size_t)(row0 + row) * NDIM + c4 * 4]) =
            *reinterpret_cast<const float4*>(&tb[row * NDIM + c4 * 4]);
    }
    if (t < 128) {
        const float A = expf(logA[t]);
        float h = 0.f;
#pragma unroll
        for (int j = 0; j < CHUNK; ++j)
            h = fmaf(A, h, tb[j * NDIM + t]);
        agg[(size_t)blockIdx.x * NDIM + t] = h;
    }
}

// ---------------- scan phase 2: carries across chunks ----------------
__global__ void scan_carry(const float* __restrict__ agg, const float* __restrict__ logA,
                           float* __restrict__ hprev) {
    const int idx = blockIdx.x * blockDim.x + threadIdx.x;  // 1024 total
    const int b = idx >> 7, n = idx & 127;
    const float Ac = expf((float)CHUNK * logA[n]);
    float c = 0.f;
#pragma unroll 8
    for (int ch = 0; ch < NCHUNK; ++ch) {
        int g = (b * NCHUNK + ch) * NDIM + n;
        hprev[g] = c;
        c = fmaf(Ac, c, agg[g]);
    }
}

// ---------------- scan phase 3: final scan, write hs (f16) ----------------
__global__ void scan_final(const float* __restrict__ xp, const float* __restrict__ logA,
                           const float* __restrict__ hprev, _Float16* __restrict__ hs) {
    const int chunk = blockIdx.x;
    const int n = threadIdx.x;
    const float A = expf(logA[n]);
    float h = hprev[chunk * NDIM + n];
    const float* u = xp + (size_t)chunk * CHUNK * NDIM + n;
    _Float16* o = hs + (size_t)chunk * CHUNK * NDIM + n;
#pragma unroll
    for (int j = 0; j < CHUNK; ++j) {
        h = fmaf(A, h, u[j * NDIM]);
        o[j * NDIM] = (_Float16)h;
    }
}

// ---------------- GEMM2: y = hs @ Cw^T + x*Dp ----------------
// 128x128 tile, K=128. hs panel [128][128] f16 DMA-staged, XOR-swizzled
// (chunk ^= row&7, pre-swizzled global source). Cwh fragments direct from L2.
// 34 KB LDS (panel overlaid by epilogue buf) -> 4 blocks/CU.
// Bijective XCD swizzle: XCD c owns row-panels c*32..c*32+31 (1 MB hs slab in L2).
#define BUFW 132
__global__ __launch_bounds__(256, 4) void gemm2(const _Float16* __restrict__ hs,
                                                const _Float16* __restrict__ Cwh,
                                                const float* __restrict__ x,
                                                const float* __restrict__ Dp,
                                                float* __restrict__ y) {
    __shared__ __align__(16) char smem[64 * BUFW * 4];   // 33792 B; hs panel uses first 32768
    __shared__ __align__(16) float DpS[128];
    _Float16* hsP = (_Float16*)smem;

    const int t = threadIdx.x;
    const int id = blockIdx.x;                     // 2048 = 256 row-blocks x 8 col-blocks
    const int xb = (id & 7) * 32 + ((id >> 3) & 31);
    const int yb = id >> 8;
    const int row0 = xb * 128;
    const int col0 = yb * 128;
    const int wave = t >> 6, lane = t & 63;
    const int wr = (wave >> 1) * 64, wc = (wave & 1) * 64;
    const int lrow = lane & 15, kq = (lane >> 4) * 8;

    if (t < 128) DpS[t] = Dp[col0 + t];

    // DMA hs panel: [128][128] f16, 16 chunks/row, source chunk pre-swizzled
#pragma unroll
    for (int inst = 0; inst < 8; ++inst) {
        int s = inst * 256 + t;
        int r = s >> 4, c = s & 15;
        dma16(&hs[(size_t)(row0 + r) * NDIM + ((c ^ (r & 7)) * 8)],
              &hsP[(inst * 256 + wave * 64) * 8]);
    }
    __syncthreads();

    const _Float16* cb = Cwh + (size_t)(col0 + wc + lrow) * NDIM + kq;

    f32x4 acc[4][4] = {};
#pragma unroll
    for (int kb = 0; kb < 4; ++kb) {
        half8 bf[4], af[4];
#pragma unroll
        for (int ct = 0; ct < 4; ++ct)
            bf[ct] = *reinterpret_cast<const half8*>(cb + (size_t)ct * 16 * NDIM + kb * 32);
#pragma unroll
        for (int rt = 0; rt < 4; ++rt) {
            int ar = wr + rt * 16 + lrow;
            int ck = kb * 4 + (kq >> 3);
            af[rt] = *reinterpret_cast<const half8*>(&hsP[ar * NDIM + ((ck ^ (ar & 7)) * 8)]);
        }
#pragma unroll
        for (int rt = 0; rt < 4; ++rt)
#pragma unroll
            for (int ct = 0; ct < 4; ++ct)
                acc[rt][ct] = __builtin_amdgcn_mfma_f32_16x16x32_f16(af[rt], bf[ct], acc[rt][ct], 0, 0, 0);
    }

    // epilogue: two 64-row halves through LDS fp32 buffer (overlays hs panel)
    float* buf = (float*)smem;
    const int q4 = (lane >> 4) * 4;
#pragma unroll
    for (int half_ = 0; half_ < 2; ++half_) {
        __syncthreads();
        if ((wr >> 6) == half_) {
#pragma unroll
            for (int rt = 0; rt < 4; ++rt)
#pragma unroll
                for (int ct = 0; ct < 4; ++ct) {
                    int col = wc + ct * 16 + lrow;
#pragma unroll
                    for (int i = 0; i < 4; ++i)
                        buf[(rt * 16 + q4 + i) * BUFW + col] = acc[rt][ct][i];
                }
        }
        __syncthreads();
#pragma unroll
        for (int j = 0; j < 8; ++j) {
            int idx = t + 256 * j;
            int row = idx >> 5, c4 = idx & 31;
            int grow = row0 + half_ * 64 + row;
            float4 a = *reinterpret_cast<const float4*>(&buf[row * BUFW + c4 * 4]);
            float4 xv = *reinterpret_cast<const float4*>(&x[(size_t)grow * DDIM + col0 + c4 * 4]);
            float4 dp = *reinterpret_cast<const float4*>(&DpS[c4 * 4]);
            float4 o;
            o.x = a.x + xv.x * dp.x;
            o.y = a.y + xv.y * dp.y;
            o.z = a.z + xv.z * dp.z;
            o.w = a.w + xv.w * dp.w;
            *reinterpret_cast<float4*>(&y[(size_t)grow * DDIM + col0 + c4 * 4]) = o;
        }
    }
}

extern "C" void kernel_launch(void* const* d_in, const int* in_sizes, int n_in,
                              void* d_out, int out_size, void* d_ws, size_t ws_size,
                              hipStream_t stream) {
    const float* x    = (const float*)d_in[0];   // (8, 4096, 1024)
    const float* Bw   = (const float*)d_in[1];   // (128, 1024)
    const float* Cw   = (const float*)d_in[2];   // (1024, 128)
    const float* logA = (const float*)d_in[3];   // (128,)
    const float* Dp   = (const float*)d_in[4];   // (1024,)
    float* out = (float*)d_out;                  // y (33554432) + final_state (1024)

    char* ws = (char*)d_ws;
    float*    xp    = (float*)   (ws);                       // 16,777,216 B
    _Float16* hs    = (_Float16*)(ws + 16777216);            //  8,388,608 B
    float*    agg   = (float*)   (ws + 25165824);            //    524,288 B
    float*    hprev = (float*)   (ws + 25690112);            //    524,288 B
    _Float16* Bwh   = (_Float16*)(ws + 26214400);            //    262,144 B
    _Float16* Cwh   = (_Float16*)(ws + 26476544);            //    262,144 B

    prep<<<192, 256, 0, stream>>>(x, Bw, Cw, Bwh, Cwh, out);
    gemm1<<<MTOT / 32, 256, 0, stream>>>(x, Bwh, logA, xp, agg);
    scan_carry<<<8, 128, 0, stream>>>(agg, logA, hprev);
    scan_final<<<TOTCHUNK, 128, 0, stream>>>(xp, logA, hprev, hs);
    gemm2<<<MTOT / 128 * (DDIM / 128), 256, 0, stream>>>(hs, Cwh, x, Dp, out);
}